// Round 1
// 33684.369 us; speedup vs baseline: 1.0988x; 1.0988x over previous
//
#include <hip/hip_runtime.h>
#include <math.h>

// ---------------------------------------------------------------------------
// Persistent bidirectional batch-as-sequence LSTM tagger — round 6.
//
// Structure: EXACTLY round 5 (known good, 37.0 ms). ONLY the LL consume
// width changed:
//   round 5: consume4 = 4x 8-B agent-scope atomic loads per thread per
//            buffer -> 262K MALL transactions per dir-step (poll traffic
//            dominates: ~6 us/step transport at 22% VALUBusy)
//   round 6: consume4w = 2x 16-B global_load_dwordx4 sc1 (one transaction
//            covers TWO {payload,gen} packets; publishes remain single 8-B
//            atomic stores so packet atomicity is unchanged; each 8-B half
//            of an aligned 16-B load is read whole at the coherence point).
//            -> 131K transactions per dir-step, same protocol, no fences.
// Slot safety argument unchanged: H0/H1 use 2 slots keyed by k&1 (18 even
// => fixed mapping); a slot written at step g is rewritten at g+2, and the
// g+2 publisher has passed step g+1's full-WG consume, which transitively
// requires every WG to have consumed slot g. PREV double-buffers by t&1.
// ---------------------------------------------------------------------------

constexpr int B_   = 16;
constexpr int S_   = 256;
constexpr int E_   = 512;
constexpr int H_   = 1024;
constexpr int T_   = 64;
constexpr int DIN0 = E_ + T_;     // 576
constexpr int NTHR = 256;
constexpr int NWGD = 128;
constexpr int UPW  = 8;
constexpr int ROWS = 32;
constexpr unsigned MAGIC = 0x13572468u;

// LDS byte offsets
constexpr int OFF_W0    = 0;        // uint4[16*256]  Whh0 bf16 swizzled
constexpr int OFF_W1    = 65536;    // uint4[16*256]  Whh1
constexpr int OFF_HB0   = 131072;   // float[1024]    h0 stage
constexpr int OFF_HB1   = 135168;   // float[1024]    h1 stage
constexpr int OFF_PRE0  = 139264;   // float[16][32]
constexpr int OFF_PA    = 141312;   // float[256]
constexpr int OFF_PB    = 142336;   // float[256]
constexpr int OFF_TAGP  = 143360;   // float[256]
constexpr int OFF_PREVL = 144384;   // float[16][64]
constexpr int OFF_GROW  = 148480;   // float[64]
constexpr int OFF_BIAS  = 148736;   // float[64]
constexpr int OFF_CELL  = 148992;   // float[16]
constexpr int SMEM_SZ   = 149120;

// workspace BYTE offsets
constexpr size_t WS_OUTD = 0;                    // float[2][256][16][64] = 2 MB
constexpr size_t WS_H0LL = 2097152;              // ull[2dir][2slot][1024]
constexpr size_t WS_H1LL = WS_H0LL + 32768;      // ull[2dir][2slot][1024]
constexpr size_t WS_PRLL = WS_H1LL + 32768;      // ull[2dir][2buf][1024]
constexpr size_t WS_BST  = WS_PRLL + 32768;      // ints[8]

struct Params {
  const float* x;
  const float* Wih0[2]; const float* Whh0[2];
  const float* bih0[2]; const float* bhh0[2];
  const float* Wih1[2]; const float* Whh1[2];
  const float* bih1[2]; const float* bhh1[2];
  const float* Wtg[2];  const float* btg[2];
  float* out; float* ws;
};

__device__ __forceinline__ float sigf(float x) { return 1.0f / (1.0f + expf(-x)); }

__device__ __forceinline__ unsigned short f2bf_rtn(float f) {
  unsigned u = __float_as_uint(f);
  unsigned r = (u + 0x7fffu + ((u >> 16) & 1u)) >> 16;
  return (unsigned short)r;
}
__device__ __forceinline__ unsigned pk2(float a, float b) {
  return (unsigned)f2bf_rtn(a) | ((unsigned)f2bf_rtn(b) << 16);
}

__device__ __forceinline__ float d8(uint4 u, float4 a, float4 b) {
  float s;
  s  = __uint_as_float(u.x << 16) * a.x + __uint_as_float(u.x & 0xffff0000u) * a.y;
  s += __uint_as_float(u.y << 16) * a.z + __uint_as_float(u.y & 0xffff0000u) * a.w;
  s += __uint_as_float(u.z << 16) * b.x + __uint_as_float(u.z & 0xffff0000u) * b.y;
  s += __uint_as_float(u.w << 16) * b.z + __uint_as_float(u.w & 0xffff0000u) * b.w;
  return s;
}

// ---- LL primitives: publish = ONE 8-B atomic {fp32, u32 gen} ----
__device__ __forceinline__ void llst(unsigned long long* p, float v, unsigned gen) {
  unsigned long long pkt =
      (unsigned long long)__float_as_uint(v) | ((unsigned long long)gen << 32);
  __hip_atomic_store(p, pkt, __ATOMIC_RELAXED, __HIP_MEMORY_SCOPE_AGENT);
}

// Wide consume: one 16-B sc1 load = two {payload, gen} packets (one MALL
// transaction at the coherence point; each aligned 8-B half is non-torn).
typedef unsigned int u32x4 __attribute__((ext_vector_type(4)));

__device__ __forceinline__ u32x4 ll_ld16(const unsigned long long* p) {
  u32x4 v;
  asm volatile("global_load_dwordx4 %0, %1, off sc1\n\t"
               "s_waitcnt vmcnt(0)"
               : "=v"(v) : "v"(p) : "memory");
  return v;
}

__device__ __forceinline__ void consume4w(const unsigned long long* src,
                                          unsigned gen, float* dst) {
  u32x4 q0, q1;
  asm volatile("global_load_dwordx4 %0, %2, off sc1\n\t"
               "global_load_dwordx4 %1, %3, off sc1\n\t"
               "s_waitcnt vmcnt(0)"
               : "=v"(q0), "=v"(q1)
               : "v"(src), "v"(src + 2) : "memory");
  while (q0.y != gen || q0.w != gen) q0 = ll_ld16(src);
  while (q1.y != gen || q1.w != gen) q1 = ll_ld16(src + 2);
  dst[0] = __uint_as_float(q0.x);
  dst[1] = __uint_as_float(q0.z);
  dst[2] = __uint_as_float(q1.x);
  dst[3] = __uint_as_float(q1.z);
}

// One-time barrier (final combine only) — known-good from rounds 1/3.
__device__ __forceinline__ void dbar(int* cnt, int* gen, int n) {
  __threadfence();
  __syncthreads();
  if (threadIdx.x == 0) {
    int g = __hip_atomic_load(gen, __ATOMIC_RELAXED, __HIP_MEMORY_SCOPE_AGENT);
    int a = __hip_atomic_fetch_add(cnt, 1, __ATOMIC_ACQ_REL, __HIP_MEMORY_SCOPE_AGENT);
    if (a == n - 1) {
      __hip_atomic_store(cnt, 0, __ATOMIC_RELAXED, __HIP_MEMORY_SCOPE_AGENT);
      __hip_atomic_store(gen, g + 1, __ATOMIC_RELEASE, __HIP_MEMORY_SCOPE_AGENT);
    } else {
      while (__hip_atomic_load(gen, __ATOMIC_ACQUIRE, __HIP_MEMORY_SCOPE_AGENT) == g)
        __builtin_amdgcn_s_sleep(2);
    }
  }
  __syncthreads();
}

__global__ void __launch_bounds__(NTHR, 1) lstm_kernel(Params p) {
  extern __shared__ char smem[];
  uint4* w0m   = (uint4*)(smem + OFF_W0);
  uint4* w1m   = (uint4*)(smem + OFF_W1);
  float* hbuf0 = (float*)(smem + OFF_HB0);
  float* hbuf1 = (float*)(smem + OFF_HB1);
  float* pre0  = (float*)(smem + OFF_PRE0);
  float* partA = (float*)(smem + OFF_PA);
  float* partB = (float*)(smem + OFF_PB);
  float* tagp  = (float*)(smem + OFF_TAGP);
  float* prevL = (float*)(smem + OFF_PREVL);
  float* grow  = (float*)(smem + OFF_GROW);
  float* bias  = (float*)(smem + OFF_BIAS);
  float* cell  = (float*)(smem + OFF_CELL);

  const int tid = threadIdx.x;
  const int wg  = blockIdx.x;
  const int dir = wg >> 7;
  const int w   = wg & (NWGD - 1);
  const int o   = tid >> 5;                            // k-chunk 0..7
  const int r   = tid & 31;                            // gate-row 0..31
  const int R   = (r >> 3) * H_ + w * UPW + (r & 7);   // global gate row

  const float* Wih0 = p.Wih0[dir];
  const float* Whh0 = p.Whh0[dir];
  const float* Wih1 = p.Wih1[dir];
  const float* Whh1 = p.Whh1[dir];
  const float* Wtg  = p.Wtg[dir];
  const float* btg  = p.btg[dir];

  char* wsb = (char*)p.ws;
  float* OUTD = (float*)(wsb + WS_OUTD);
  unsigned long long* H0LL = (unsigned long long*)(wsb + WS_H0LL) + dir * 2048;
  unsigned long long* H1LL = (unsigned long long*)(wsb + WS_H1LL) + dir * 2048;
  unsigned long long* PRLL = (unsigned long long*)(wsb + WS_PRLL) + dir * 2048;
  int* bst = (int*)(wsb + WS_BST);

  // ---- bst init handshake (for the final dbar; ws poisoned 0xAA) ----
  if (tid == 0) {
    if (wg == 0) {
#pragma unroll
      for (int i = 0; i < 6; ++i)
        __hip_atomic_store(bst + i, 0, __ATOMIC_RELAXED, __HIP_MEMORY_SCOPE_AGENT);
      __hip_atomic_store(bst + 6, (int)MAGIC, __ATOMIC_RELEASE, __HIP_MEMORY_SCOPE_AGENT);
    } else {
      while (__hip_atomic_load(bst + 6, __ATOMIC_ACQUIRE, __HIP_MEMORY_SCOPE_AGENT) != (int)MAGIC)
        __builtin_amdgcn_s_sleep(8);
    }
  }

  // ---- stage Whh0/Whh1 into LDS (bf16, thread-read order); Wih1 into VGPRs
  uint4 wih1r[16];
#pragma unroll 1
  for (int j = 0; j < 16; ++j) {
    const float* s0 = Whh0 + (size_t)R * H_ + o * 128 + j * 8;
    uint4 u;
    u.x = pk2(s0[0], s0[1]); u.y = pk2(s0[2], s0[3]);
    u.z = pk2(s0[4], s0[5]); u.w = pk2(s0[6], s0[7]);
    w0m[j * NTHR + tid] = u;
    const float* s1 = Whh1 + (size_t)R * H_ + o * 128 + j * 8;
    u.x = pk2(s1[0], s1[1]); u.y = pk2(s1[2], s1[3]);
    u.z = pk2(s1[4], s1[5]); u.w = pk2(s1[6], s1[7]);
    w1m[j * NTHR + tid] = u;
    const float* s2 = Wih1 + (size_t)R * H_ + o * 128 + j * 8;
    u.x = pk2(s2[0], s2[1]); u.y = pk2(s2[2], s2[3]);
    u.z = pk2(s2[4], s2[5]); u.w = pk2(s2[6], s2[7]);
    wih1r[j] = u;
  }
  // tag row w (WGs w<64): Wtg row in 4 fp32 regs/thread + bias
  float4 wtag = make_float4(0.f, 0.f, 0.f, 0.f);
  float btgw = 0.f;
  if (w < T_) {
    wtag = *(const float4*)(Wtg + (size_t)w * H_ + tid * 4);
    btgw = btg[w];
  }
  if (tid < ROWS) {
    int Rr = (tid >> 3) * H_ + w * UPW + (tid & 7);
    bias[tid]        = p.bih0[dir][Rr] + p.bhh0[dir][Rr];
    bias[ROWS + tid] = p.bih1[dir][Rr] + p.bhh1[dir][Rr];
  }
  if (tid < 16) cell[tid] = 0.f;
  // initial h state = 0 (local; LL gens gate all cross-WG reads)
  ((float4*)hbuf0)[tid] = make_float4(0.f, 0.f, 0.f, 0.f);
  ((float4*)hbuf1)[tid] = make_float4(0.f, 0.f, 0.f, 0.f);
  __syncthreads();

  // =========================== outer time loop ============================
#pragma unroll 1
  for (int t = 0; t < S_; ++t) {
    const int tt = dir ? (S_ - 1 - t) : t;

    // ---- Phase A: pre0[b][r] = bias0 + Wih0_x.x_t[b] (+ Wih0_tag.prev[b])
    {
      const int b  = tid >> 4, rh = tid & 15;
      const int r0 = 2 * rh, r1 = 2 * rh + 1;
      const int R0 = (r0 >> 3) * H_ + w * UPW + (r0 & 7);
      const int R1 = (r1 >> 3) * H_ + w * UPW + (r1 & 7);
      const float4* w0p = (const float4*)(Wih0 + (size_t)R0 * DIN0);
      const float4* w1p = (const float4*)(Wih0 + (size_t)R1 * DIN0);
      const float4* xp  = (const float4*)(p.x + ((size_t)b * S_ + tt) * E_);
      float s0 = bias[r0], s1 = bias[r1];
#pragma unroll 8
      for (int i = 0; i < 128; ++i) {
        float4 xv = xp[i], a = w0p[i], c = w1p[i];
        s0 += a.x * xv.x + a.y * xv.y + a.z * xv.z + a.w * xv.w;
        s1 += c.x * xv.x + c.y * xv.y + c.z * xv.z + c.w * xv.w;
      }
      if (t > 0) {
        const float4* pv = (const float4*)(prevL + b * T_);
        const float4* q0 = (const float4*)(Wih0 + (size_t)R0 * DIN0 + E_);
        const float4* q1 = (const float4*)(Wih0 + (size_t)R1 * DIN0 + E_);
#pragma unroll
        for (int i = 0; i < 16; ++i) {
          float4 pvv = pv[i], a = q0[i], c = q1[i];
          s0 += a.x * pvv.x + a.y * pvv.y + a.z * pvv.z + a.w * pvv.w;
          s1 += c.x * pvv.x + c.y * pvv.y + c.z * pvv.z + c.w * pvv.w;
        }
      }
      pre0[b * ROWS + r0] = s0;
      pre0[b * ROWS + r1] = s1;
      __syncthreads();
    }

    // ---- 18 pipelined steps: L0(b=k), L1(b=k-1), tag(b=k-2) ----
#pragma unroll 1
    for (int k = 0; k < 18; ++k) {
      const unsigned gen  = (unsigned)(t * 18 + k) + 1u;
      const int      slot = (k & 1) << 10;

      float acc0 = 0.f, accB = 0.f;
      const float4* hb0 = ((const float4*)hbuf0) + o * 32;
      const float4* hb1 = ((const float4*)hbuf1) + o * 32;
      if (k >= 1 && k < 16) {
#pragma unroll
        for (int j = 0; j < 16; ++j) {
          float4 a0 = hb0[2 * j], a1 = hb0[2 * j + 1];
          acc0 += d8(w0m[j * NTHR + tid], a0, a1);
          accB += d8(wih1r[j], a0, a1);
          float4 b0 = hb1[2 * j], b1 = hb1[2 * j + 1];
          accB += d8(w1m[j * NTHR + tid], b0, b1);
        }
      } else if (k == 0) {
#pragma unroll
        for (int j = 0; j < 16; ++j) {
          float4 a0 = hb0[2 * j], a1 = hb0[2 * j + 1];
          acc0 += d8(w0m[j * NTHR + tid], a0, a1);
        }
      } else if (k == 16) {
#pragma unroll
        for (int j = 0; j < 16; ++j) {
          float4 a0 = hb0[2 * j], a1 = hb0[2 * j + 1];
          accB += d8(wih1r[j], a0, a1);
          float4 b0 = hb1[2 * j], b1 = hb1[2 * j + 1];
          accB += d8(w1m[j * NTHR + tid], b0, b1);
        }
      }
      // k == 17: no recurrence dots

      // tag partial for b = k-2 (hbuf1 == h1(b=k-2)); WGs w<64 own row w
      float tagd = 0.f;
      if (k >= 2 && w < T_) {
        float4 hv = *(const float4*)(hbuf1 + tid * 4);
        tagd = wtag.x * hv.x + wtag.y * hv.y + wtag.z * hv.z + wtag.w * hv.w;
      }

      partA[tid] = acc0;
      partB[tid] = accB;
      tagp[tid]  = tagd;
      __syncthreads();               // S1: dots done (hbuf free), partials out

      // ---- wave-0 reductions (round-3 layout) ----
      if (tid < 32) {
        if (k < 16) {
          float s = pre0[k * ROWS + tid];
#pragma unroll
          for (int oo = 0; oo < 8; ++oo) s += partA[oo * 32 + tid];
          grow[tid] = s;
        }
      } else if (tid < 64) {
        int rr = tid - 32;
        if (k >= 1 && k < 17) {
          float s = bias[ROWS + rr];
#pragma unroll
          for (int oo = 0; oo < 8; ++oo) s += partB[oo * 32 + rr];
          grow[32 + rr] = s;
        }
      }
      if (k >= 2 && w < T_ && tid < 64) {
        float ts = tagp[tid] + tagp[64 + tid] + tagp[128 + tid] + tagp[192 + tid];
#pragma unroll
        for (int d = 32; d >= 1; d >>= 1) ts += __shfl_xor(ts, d, 64);
        if (tid == 0) {
          const int b = k - 2;
          float val = ts + btgw;
          OUTD[(((size_t)dir * S_ + tt) * B_ + b) * T_ + w] = val;  // plain
          llst(PRLL + ((t & 1) << 10) + b * T_ + w, val, (unsigned)(t + 1));
        }
      }
      __syncthreads();               // S2: grow visible (round-3 placement)

      // ---- cell updates + LL publishes ----
      if (k < 16 && tid < UPW) {
        int u = tid;
        float gi = grow[u], gf = grow[8 + u], gg = grow[16 + u], go = grow[24 + u];
        float cc = sigf(gf) * cell[u] + sigf(gi) * tanhf(gg);
        float hh = sigf(go) * tanhf(cc);
        cell[u] = cc;
        llst(H0LL + slot + w * UPW + u, hh, gen);
      }
      if (k >= 1 && k < 17 && tid >= UPW && tid < 16) {
        int u = tid - UPW;
        float gi = grow[32 + u], gf = grow[40 + u], gg = grow[48 + u], go = grow[56 + u];
        float cc = sigf(gf) * cell[8 + u] + sigf(gi) * tanhf(gg);
        float hh = sigf(go) * tanhf(cc);
        cell[8 + u] = cc;
        llst(H1LL + slot + w * UPW + u, hh, gen);
      }

      // ---- LL consume into hbuf/prevL (data arrives with its gen) ----
      if (k < 16)
        consume4w(H0LL + slot + tid * 4, gen, hbuf0 + tid * 4);
      if (k >= 1 && k < 17)
        consume4w(H1LL + slot + tid * 4, gen, hbuf1 + tid * 4);
      if (k == 17)
        consume4w(PRLL + ((t & 1) << 10) + tid * 4, (unsigned)(t + 1),
                  prevL + tid * 4);
      __syncthreads();               // S3: hbuf/prevL coherent for next step
    }
  }

  // ---- both directions done: combine + log_softmax (round-3 verbatim) ----
  dbar(bst + 2, bst + 3, 2 * NWGD);

  const int wave = tid >> 6, lane = tid & 63;
#pragma unroll 1
  for (int i = wave; i < 16; i += 4) {
    int row = wg * 16 + i;        // row = bb*S_ + ss over (B,S)
    int bb = row >> 8, ss = row & 255;
    float z = OUTD[(((size_t)0 * S_ + ss) * B_ + bb) * T_ + lane]
            + OUTD[(((size_t)1 * S_ + ss) * B_ + bb) * T_ + lane];
    float m = z;
#pragma unroll
    for (int d = 32; d >= 1; d >>= 1) m = fmaxf(m, __shfl_xor(m, d, 64));
    float e = expf(z - m);
    float sum = e;
#pragma unroll
    for (int d = 32; d >= 1; d >>= 1) sum += __shfl_xor(sum, d, 64);
    p.out[(size_t)row * T_ + lane] = (z - m) - logf(sum);
  }
}

extern "C" void kernel_launch(void* const* d_in, const int* in_sizes, int n_in,
                              void* d_out, int out_size, void* d_ws, size_t ws_size,
                              hipStream_t stream) {
  (void)in_sizes; (void)n_in; (void)out_size; (void)ws_size;
  Params prm;
  prm.x = (const float*)d_in[0];
  for (int d = 0; d < 2; ++d) {
    int base = 1 + d * 10;
    prm.Wih0[d] = (const float*)d_in[base + 0];
    prm.Whh0[d] = (const float*)d_in[base + 1];
    prm.bih0[d] = (const float*)d_in[base + 2];
    prm.bhh0[d] = (const float*)d_in[base + 3];
    prm.Wih1[d] = (const float*)d_in[base + 4];
    prm.Whh1[d] = (const float*)d_in[base + 5];
    prm.bih1[d] = (const float*)d_in[base + 6];
    prm.bhh1[d] = (const float*)d_in[base + 7];
    prm.Wtg[d]  = (const float*)d_in[base + 8];
    prm.btg[d]  = (const float*)d_in[base + 9];
  }
  prm.out = (float*)d_out;
  prm.ws  = (float*)d_ws;

  hipFuncSetAttribute((const void*)lstm_kernel,
                      hipFuncAttributeMaxDynamicSharedMemorySize, SMEM_SZ);
  void* kp[] = { &prm };
  hipLaunchCooperativeKernel((const void*)lstm_kernel, dim3(2 * NWGD), dim3(NTHR),
                             kp, SMEM_SZ, stream);
}